// Round 1
// baseline (6183.727 us; speedup 1.0000x reference)
//
#include <hip/hip_runtime.h>
#include <math.h>

#define NBLK    256
#define NTHR    256
#define HDIM    2048
#define TSTEPS  256
#define BBASIS  8

// Persistent-grid Elman scan.
// Partition: block owns 8 rows of h; wave w owns rows j0 = bid*8 + 2w, j0+1.
// Lane l covers columns c = l*4 + 256k + i (k=0..7, i=0..3) -> float4 index l + 64k.
__global__ __launch_bounds__(NTHR, 1)
void elman_scan_kernel(const float* __restrict__ x,        // [256][2048]
                       const float* __restrict__ W,        // [8][2048][2048]
                       const float* __restrict__ alphas,   // [8][8]
                       const float* __restrict__ bias,     // [2048]
                       const float* __restrict__ v,        // [2048][2048]
                       const float* __restrict__ fc_w,     // [2048][2048]
                       const float* __restrict__ fc_b,     // [2048]
                       const int*   __restrict__ alpha_int,
                       float*       __restrict__ out,      // [2048]
                       unsigned int* __restrict__ flags,   // [NBLK], zeroed each launch
                       float*       __restrict__ hbuf)     // [2][2048]
{
    const int tid  = threadIdx.x;
    const int bid  = blockIdx.x;
    const int wave = tid >> 6;
    const int lane = tid & 63;
    const int j0   = bid * 8 + wave * 2;   // this wave's two output rows
    const int j1   = j0 + 1;

    __shared__ __align__(16) float h_lds[HDIM];          // 8 KB, current h
    __shared__ float ig_lds[8][TSTEPS];                  // 8 KB, igates for this block's rows

    // ---- alpha = softmax(alphas[alpha_int]) (redundant per thread, trivial) ----
    const int ai = alpha_int[0];
    float a[BBASIS];
    float mx = -1e30f;
    #pragma unroll
    for (int b = 0; b < BBASIS; ++b) { a[b] = alphas[ai * BBASIS + b]; mx = fmaxf(mx, a[b]); }
    float ssum = 0.f;
    #pragma unroll
    for (int b = 0; b < BBASIS; ++b) { a[b] = expf(a[b] - mx); ssum += a[b]; }
    const float inv_s = 1.f / ssum;

    // ---- igates: ig_lds[r][t] = dot(x[t,:], v[j,:]) for this wave's 2 rows ----
    {
        float vr[2][8][4];
        #pragma unroll
        for (int j2 = 0; j2 < 2; ++j2) {
            const float4* vrow = (const float4*)(v + (size_t)(j0 + j2) * HDIM);
            #pragma unroll
            for (int k = 0; k < 8; ++k) {
                float4 t4 = vrow[lane + 64 * k];
                vr[j2][k][0] = t4.x; vr[j2][k][1] = t4.y; vr[j2][k][2] = t4.z; vr[j2][k][3] = t4.w;
            }
        }
        for (int t = 0; t < TSTEPS; ++t) {
            const float4* xt = (const float4*)(x + (size_t)t * HDIM);
            float acc0 = 0.f, acc1 = 0.f;
            #pragma unroll
            for (int k = 0; k < 8; ++k) {
                float4 x4 = xt[lane + 64 * k];
                acc0 += vr[0][k][0]*x4.x + vr[0][k][1]*x4.y + vr[0][k][2]*x4.z + vr[0][k][3]*x4.w;
                acc1 += vr[1][k][0]*x4.x + vr[1][k][1]*x4.y + vr[1][k][2]*x4.z + vr[1][k][3]*x4.w;
            }
            #pragma unroll
            for (int off = 32; off > 0; off >>= 1) {
                acc0 += __shfl_xor(acc0, off, 64);
                acc1 += __shfl_xor(acc1, off, 64);
            }
            if (lane == 0) {
                ig_lds[wave * 2 + 0][t] = acc0;
                ig_lds[wave * 2 + 1][t] = acc1;
            }
        }
    }

    // ---- u = sum_b alpha[b] * W[b], rows j0/j1 into registers ----
    float u_reg[2][8][4];
    #pragma unroll
    for (int j2 = 0; j2 < 2; ++j2)
        #pragma unroll
        for (int k = 0; k < 8; ++k)
            #pragma unroll
            for (int i = 0; i < 4; ++i) u_reg[j2][k][i] = 0.f;

    for (int b = 0; b < BBASIS; ++b) {
        const float ab = a[b] * inv_s;
        #pragma unroll
        for (int j2 = 0; j2 < 2; ++j2) {
            const float4* wrow = (const float4*)(W + ((size_t)b * HDIM + (size_t)(j0 + j2)) * HDIM);
            #pragma unroll
            for (int k = 0; k < 8; ++k) {
                float4 w4 = wrow[lane + 64 * k];
                u_reg[j2][k][0] += ab * w4.x;
                u_reg[j2][k][1] += ab * w4.y;
                u_reg[j2][k][2] += ab * w4.z;
                u_reg[j2][k][3] += ab * w4.w;
            }
        }
    }
    const float bias0 = bias[j0], bias1 = bias[j1];

    // ---- h0 = 0 ----
    for (int i = tid; i < HDIM; i += NTHR) h_lds[i] = 0.f;
    __syncthreads();

    // ---- sequential scan with grid-wide flag barrier per step ----
    for (int t = 0; t < TSTEPS; ++t) {
        float acc0 = 0.f, acc1 = 0.f;
        #pragma unroll
        for (int k = 0; k < 8; ++k) {
            const float4 h4 = ((const float4*)h_lds)[lane + 64 * k];
            acc0 += u_reg[0][k][0]*h4.x + u_reg[0][k][1]*h4.y + u_reg[0][k][2]*h4.z + u_reg[0][k][3]*h4.w;
            acc1 += u_reg[1][k][0]*h4.x + u_reg[1][k][1]*h4.y + u_reg[1][k][2]*h4.z + u_reg[1][k][3]*h4.w;
        }
        #pragma unroll
        for (int off = 32; off > 0; off >>= 1) {
            acc0 += __shfl_xor(acc0, off, 64);
            acc1 += __shfl_xor(acc1, off, 64);
        }
        const int wp = (t + 1) & 1;        // parity of buffer holding h_{t+1}
        if (lane == 0) {
            float hn0 = tanhf(acc0 + ig_lds[wave * 2 + 0][t] + bias0);
            float hn1 = tanhf(acc1 + ig_lds[wave * 2 + 1][t] + bias1);
            *(float2*)(&hbuf[wp * HDIM + j0]) = make_float2(hn0, hn1);
        }
        __syncthreads();   // all 4 waves' h stores issued & complete (vmcnt drained)
        if (tid == 0) {
            // release: flush this XCD's L2 (our 8 h floats) to L3, then publish epoch
            __hip_atomic_store(&flags[bid], (unsigned)(t + 1),
                               __ATOMIC_RELEASE, __HIP_MEMORY_SCOPE_AGENT);
        }
        const unsigned tgt = (unsigned)(t + 1);
        // thread i waits on block i's flag; coherent (agent-scope) loads bypass stale L2
        while (__hip_atomic_load(&flags[tid], __ATOMIC_RELAXED, __HIP_MEMORY_SCOPE_AGENT) < tgt) { }
        __threadfence();   // acquire: invalidate L1/L2 so h reads see fresh data
        __syncthreads();   // whole block past barrier

        // stage h_{t+1} (global, fresh) -> LDS; 2-way-or-less bank pattern
        const float4* hg = (const float4*)(&hbuf[wp * HDIM]);
        float4 ha = hg[tid];
        float4 hb = hg[256 + tid];
        ((float4*)h_lds)[tid]       = ha;
        ((float4*)h_lds)[256 + tid] = hb;
        __syncthreads();
    }

    // ---- out = sigmoid(h @ fc_w.T + fc_b) ----
    {
        float acc0 = 0.f, acc1 = 0.f;
        const float4* f0 = (const float4*)(fc_w + (size_t)j0 * HDIM);
        const float4* f1 = (const float4*)(fc_w + (size_t)j1 * HDIM);
        #pragma unroll
        for (int k = 0; k < 8; ++k) {
            const float4 h4 = ((const float4*)h_lds)[lane + 64 * k];
            float4 w0 = f0[lane + 64 * k];
            float4 w1 = f1[lane + 64 * k];
            acc0 += w0.x*h4.x + w0.y*h4.y + w0.z*h4.z + w0.w*h4.w;
            acc1 += w1.x*h4.x + w1.y*h4.y + w1.z*h4.z + w1.w*h4.w;
        }
        #pragma unroll
        for (int off = 32; off > 0; off >>= 1) {
            acc0 += __shfl_xor(acc0, off, 64);
            acc1 += __shfl_xor(acc1, off, 64);
        }
        if (lane == 0) {
            out[j0] = 1.f / (1.f + expf(-(acc0 + fc_b[j0])));
            out[j1] = 1.f / (1.f + expf(-(acc1 + fc_b[j1])));
        }
    }
}

extern "C" void kernel_launch(void* const* d_in, const int* in_sizes, int n_in,
                              void* d_out, int out_size, void* d_ws, size_t ws_size,
                              hipStream_t stream)
{
    const float* x      = (const float*)d_in[0];
    const float* W      = (const float*)d_in[1];
    const float* alphas = (const float*)d_in[2];
    const float* bias   = (const float*)d_in[3];
    const float* v      = (const float*)d_in[4];
    const float* fc_w   = (const float*)d_in[5];
    const float* fc_b   = (const float*)d_in[6];
    const int*   ai     = (const int*)d_in[7];
    float* out = (float*)d_out;

    unsigned int* flags = (unsigned int*)d_ws;              // 1 KB
    float*        hbuf  = (float*)((char*)d_ws + 1024);     // 16 KB double buffer

    // flags must start at 0 every launch (d_ws is poisoned 0xAA, replays don't reset)
    hipMemsetAsync(d_ws, 0, 1024, stream);

    elman_scan_kernel<<<NBLK, NTHR, 0, stream>>>(x, W, alphas, bias, v, fc_w, fc_b,
                                                 ai, out, flags, hbuf);
}

// Round 2
// 1734.790 us; speedup vs baseline: 3.5645x; 3.5645x over previous
//
#include <hip/hip_runtime.h>
#include <math.h>

#define NBLK    256
#define NTHR    256
#define HDIM    2048
#define TSTEPS  256
#define BBASIS  8

typedef float f32x4 __attribute__((ext_vector_type(4)));
typedef float f32x2 __attribute__((ext_vector_type(2)));

// Coherent (L3-level) 16B load: sc0 sc1 bypass stale L1/L2. Two loads, one wait.
__device__ inline void load_coherent_2xf4(const float* p0, const float* p1,
                                          f32x4& a, f32x4& b) {
    asm volatile(
        "global_load_dwordx4 %0, %2, off sc0 sc1\n\t"
        "global_load_dwordx4 %1, %3, off sc0 sc1\n\t"
        "s_waitcnt vmcnt(0)"
        : "=&v"(a), "=&v"(b)
        : "v"(p0), "v"(p1)
        : "memory");
}

// Coherent 8B store: write-through past L2 so other XCDs can see it via L3.
__device__ inline void store_coherent_f2(float* p, f32x2 v) {
    asm volatile("global_store_dwordx2 %0, %1, off sc0 sc1"
                 :: "v"(p), "v"(v) : "memory");
}

// Persistent-grid Elman scan.
// Block owns 8 rows of h; wave w owns rows j0 = bid*8 + 2w, j0+1.
// Lane l covers columns c = 4l + 256k + i (k=0..7, i=0..3) -> float4 index l + 64k.
__global__ __launch_bounds__(NTHR, 1)
void elman_scan_kernel(const float* __restrict__ x,        // [256][2048]
                       const float* __restrict__ W,        // [8][2048][2048]
                       const float* __restrict__ alphas,   // [8][8]
                       const float* __restrict__ bias,     // [2048]
                       const float* __restrict__ v,        // [2048][2048]
                       const float* __restrict__ fc_w,     // [2048][2048]
                       const float* __restrict__ fc_b,     // [2048]
                       const int*   __restrict__ alpha_int,
                       float*       __restrict__ out,      // [2048]
                       unsigned int* __restrict__ flags,   // [NBLK], zeroed each launch
                       float*       __restrict__ hbuf)     // [2][2048]
{
    const int tid  = threadIdx.x;
    const int bid  = blockIdx.x;
    const int wave = tid >> 6;
    const int lane = tid & 63;
    const int j0   = bid * 8 + wave * 2;   // this wave's two output rows
    const int j1   = j0 + 1;

    __shared__ __align__(16) float h_lds[HDIM];          // 8 KB, current h
    __shared__ float ig_lds[8][TSTEPS];                  // 8 KB, igates for this block's rows

    // ---- alpha = softmax(alphas[alpha_int]) (redundant per thread, trivial) ----
    const int ai = alpha_int[0];
    float a[BBASIS];
    float mx = -1e30f;
    #pragma unroll
    for (int b = 0; b < BBASIS; ++b) { a[b] = alphas[ai * BBASIS + b]; mx = fmaxf(mx, a[b]); }
    float ssum = 0.f;
    #pragma unroll
    for (int b = 0; b < BBASIS; ++b) { a[b] = expf(a[b] - mx); ssum += a[b]; }
    const float inv_s = 1.f / ssum;

    // ---- igates: ig_lds[r][t] = dot(x[t,:], v[j,:]) for this wave's 2 rows ----
    {
        float vr[2][8][4];
        #pragma unroll
        for (int j2 = 0; j2 < 2; ++j2) {
            const float4* vrow = (const float4*)(v + (size_t)(j0 + j2) * HDIM);
            #pragma unroll
            for (int k = 0; k < 8; ++k) {
                float4 t4 = vrow[lane + 64 * k];
                vr[j2][k][0] = t4.x; vr[j2][k][1] = t4.y; vr[j2][k][2] = t4.z; vr[j2][k][3] = t4.w;
            }
        }
        for (int t = 0; t < TSTEPS; ++t) {
            const float4* xt = (const float4*)(x + (size_t)t * HDIM);
            float acc0 = 0.f, acc1 = 0.f;
            #pragma unroll
            for (int k = 0; k < 8; ++k) {
                float4 x4 = xt[lane + 64 * k];
                acc0 += vr[0][k][0]*x4.x + vr[0][k][1]*x4.y + vr[0][k][2]*x4.z + vr[0][k][3]*x4.w;
                acc1 += vr[1][k][0]*x4.x + vr[1][k][1]*x4.y + vr[1][k][2]*x4.z + vr[1][k][3]*x4.w;
            }
            #pragma unroll
            for (int off = 32; off > 0; off >>= 1) {
                acc0 += __shfl_xor(acc0, off, 64);
                acc1 += __shfl_xor(acc1, off, 64);
            }
            if (lane == 0) {
                ig_lds[wave * 2 + 0][t] = acc0;
                ig_lds[wave * 2 + 1][t] = acc1;
            }
        }
    }

    // ---- u = sum_b alpha[b] * W[b], rows j0/j1 into registers ----
    float u_reg[2][8][4];
    #pragma unroll
    for (int j2 = 0; j2 < 2; ++j2)
        #pragma unroll
        for (int k = 0; k < 8; ++k)
            #pragma unroll
            for (int i = 0; i < 4; ++i) u_reg[j2][k][i] = 0.f;

    for (int b = 0; b < BBASIS; ++b) {
        const float ab = a[b] * inv_s;
        #pragma unroll
        for (int j2 = 0; j2 < 2; ++j2) {
            const float4* wrow = (const float4*)(W + ((size_t)b * HDIM + (size_t)(j0 + j2)) * HDIM);
            #pragma unroll
            for (int k = 0; k < 8; ++k) {
                float4 w4 = wrow[lane + 64 * k];
                u_reg[j2][k][0] += ab * w4.x;
                u_reg[j2][k][1] += ab * w4.y;
                u_reg[j2][k][2] += ab * w4.z;
                u_reg[j2][k][3] += ab * w4.w;
            }
        }
    }
    const float bias0 = bias[j0], bias1 = bias[j1];

    // ---- h0 = 0 ----
    for (int i = tid; i < HDIM; i += NTHR) h_lds[i] = 0.f;
    __syncthreads();

    // Which two blocks produce the h-slices this thread stages each step:
    // float4 idx tid -> rows 4tid..4tid+3 -> block tid>>1; idx 256+tid -> block 128+(tid>>1)
    const int fb0 = tid >> 1;
    const int fb1 = 128 + (tid >> 1);

    // ---- sequential scan; h exchanged through L3 with sc0/sc1 ops, no L2 flushes ----
    for (int t = 0; t < TSTEPS; ++t) {
        float acc0 = 0.f, acc1 = 0.f;
        #pragma unroll
        for (int k = 0; k < 8; ++k) {
            const f32x4 h4 = ((const f32x4*)h_lds)[lane + 64 * k];
            acc0 += u_reg[0][k][0]*h4.x + u_reg[0][k][1]*h4.y + u_reg[0][k][2]*h4.z + u_reg[0][k][3]*h4.w;
            acc1 += u_reg[1][k][0]*h4.x + u_reg[1][k][1]*h4.y + u_reg[1][k][2]*h4.z + u_reg[1][k][3]*h4.w;
        }
        #pragma unroll
        for (int off = 32; off > 0; off >>= 1) {
            acc0 += __shfl_xor(acc0, off, 64);
            acc1 += __shfl_xor(acc1, off, 64);
        }
        const int wp = (t + 1) & 1;        // parity of buffer holding h_{t+1}
        if (lane == 0) {
            float hn0 = tanhf(acc0 + ig_lds[wave * 2 + 0][t] + bias0);
            float hn1 = tanhf(acc1 + ig_lds[wave * 2 + 1][t] + bias1);
            f32x2 hv; hv.x = hn0; hv.y = hn1;
            store_coherent_f2(&hbuf[wp * HDIM + j0], hv);
        }
        // Drain own stores to L3, then block-wide "all waves stored & done reading h_lds"
        asm volatile("s_waitcnt vmcnt(0)" ::: "memory");
        __syncthreads();
        const unsigned tgt = (unsigned)(t + 1);
        if (tid == 0) {
            __hip_atomic_store(&flags[bid], tgt,
                               __ATOMIC_RELAXED, __HIP_MEMORY_SCOPE_AGENT);
        }
        // Wait only for the two producer blocks of the slices this thread stages
        while (__hip_atomic_load(&flags[fb0], __ATOMIC_RELAXED, __HIP_MEMORY_SCOPE_AGENT) < tgt) { }
        while (__hip_atomic_load(&flags[fb1], __ATOMIC_RELAXED, __HIP_MEMORY_SCOPE_AGENT) < tgt) { }

        // Stage h_{t+1} (coherent L3 loads) -> LDS
        const float* hg = hbuf + wp * HDIM;
        f32x4 ha, hb;
        load_coherent_2xf4(hg + 4 * tid, hg + 1024 + 4 * tid, ha, hb);
        *(f32x4*)&h_lds[4 * tid]        = ha;
        *(f32x4*)&h_lds[1024 + 4 * tid] = hb;
        __syncthreads();
    }

    // ---- out = sigmoid(h @ fc_w.T + fc_b) ----
    {
        float acc0 = 0.f, acc1 = 0.f;
        const float4* f0 = (const float4*)(fc_w + (size_t)j0 * HDIM);
        const float4* f1 = (const float4*)(fc_w + (size_t)j1 * HDIM);
        #pragma unroll
        for (int k = 0; k < 8; ++k) {
            const f32x4 h4 = ((const f32x4*)h_lds)[lane + 64 * k];
            float4 w0 = f0[lane + 64 * k];
            float4 w1 = f1[lane + 64 * k];
            acc0 += w0.x*h4.x + w0.y*h4.y + w0.z*h4.z + w0.w*h4.w;
            acc1 += w1.x*h4.x + w1.y*h4.y + w1.z*h4.z + w1.w*h4.w;
        }
        #pragma unroll
        for (int off = 32; off > 0; off >>= 1) {
            acc0 += __shfl_xor(acc0, off, 64);
            acc1 += __shfl_xor(acc1, off, 64);
        }
        if (lane == 0) {
            out[j0] = 1.f / (1.f + expf(-(acc0 + fc_b[j0])));
            out[j1] = 1.f / (1.f + expf(-(acc1 + fc_b[j1])));
        }
    }
}

extern "C" void kernel_launch(void* const* d_in, const int* in_sizes, int n_in,
                              void* d_out, int out_size, void* d_ws, size_t ws_size,
                              hipStream_t stream)
{
    const float* x      = (const float*)d_in[0];
    const float* W      = (const float*)d_in[1];
    const float* alphas = (const float*)d_in[2];
    const float* bias   = (const float*)d_in[3];
    const float* v      = (const float*)d_in[4];
    const float* fc_w   = (const float*)d_in[5];
    const float* fc_b   = (const float*)d_in[6];
    const int*   ai     = (const int*)d_in[7];
    float* out = (float*)d_out;

    unsigned int* flags = (unsigned int*)d_ws;              // 1 KB
    float*        hbuf  = (float*)((char*)d_ws + 1024);     // 16 KB double buffer

    // flags must start at 0 every launch (d_ws is poisoned 0xAA, replays don't reset)
    hipMemsetAsync(d_ws, 0, 1024, stream);

    elman_scan_kernel<<<NBLK, NTHR, 0, stream>>>(x, W, alphas, bias, v, fc_w, fc_b,
                                                 ai, out, flags, hbuf);
}

// Round 3
// 1421.609 us; speedup vs baseline: 4.3498x; 1.2203x over previous
//
#include <hip/hip_runtime.h>
#include <math.h>

#define NBLK    256
#define NTHR    256
#define HDIM    2048
#define TSTEPS  256
#define BBASIS  8

typedef float f32x4 __attribute__((ext_vector_type(4)));
typedef float f32x2 __attribute__((ext_vector_type(2)));

// Coherent 8B store: bypass L1/L2 (sc0 sc1) so all XCDs see it at L3.
__device__ inline void store_coherent_f2(float* p, f32x2 v) {
    asm volatile("global_store_dwordx2 %0, %1, off sc0 sc1"
                 :: "v"(p), "v"(v) : "memory");
}

// Poll two float4s until every word is non-sentinel (0xFFFFFFFF = memset 0xFF).
// tanh output is finite => bit pattern never equals the sentinel.
__device__ inline void poll2_f4(const float* p0, const float* p1,
                                f32x4& a, f32x4& b) {
    for (;;) {
        asm volatile(
            "global_load_dwordx4 %0, %2, off sc0 sc1\n\t"
            "global_load_dwordx4 %1, %3, off sc0 sc1\n\t"
            "s_waitcnt vmcnt(0)"
            : "=&v"(a), "=&v"(b)
            : "v"(p0), "v"(p1)
            : "memory");
        const unsigned s = 0xFFFFFFFFu;
        bool ok = (__float_as_uint(a.x) != s) & (__float_as_uint(a.y) != s) &
                  (__float_as_uint(a.z) != s) & (__float_as_uint(a.w) != s) &
                  (__float_as_uint(b.x) != s) & (__float_as_uint(b.y) != s) &
                  (__float_as_uint(b.z) != s) & (__float_as_uint(b.w) != s);
        if (ok) return;
        __builtin_amdgcn_s_sleep(1);   // back off ~64 cyc: don't saturate L3 with polls
    }
}

// Persistent-grid Elman scan, data-polling exchange (no flags, no fences).
// Block owns 8 rows of h; wave w owns rows j0 = bid*8 + 2w, j0+1.
// Lane l covers columns c = 4l + 256k + i (k=0..7, i=0..3) -> float4 index l + 64k.
__global__ __launch_bounds__(NTHR, 1)
void elman_scan_kernel(const float* __restrict__ x,        // [256][2048]
                       const float* __restrict__ W,        // [8][2048][2048]
                       const float* __restrict__ alphas,   // [8][8]
                       const float* __restrict__ bias,     // [2048]
                       const float* __restrict__ v,        // [2048][2048]
                       const float* __restrict__ fc_w,     // [2048][2048]
                       const float* __restrict__ fc_b,     // [2048]
                       const int*   __restrict__ alpha_int,
                       float*       __restrict__ out,      // [2048]
                       float*       __restrict__ hbuf)     // [TSTEPS+1][2048], 0xFF-filled
{
    const int tid  = threadIdx.x;
    const int bid  = blockIdx.x;
    const int wave = tid >> 6;
    const int lane = tid & 63;
    const int j0   = bid * 8 + wave * 2;   // this wave's two output rows
    const int j1   = j0 + 1;

    __shared__ __align__(16) float h_lds[2][HDIM];       // 16 KB double buffer
    __shared__ float ig_lds[8][TSTEPS];                  // 8 KB igates for this block's rows

    // ---- alpha = softmax(alphas[alpha_int]) (redundant per thread, trivial) ----
    const int ai = alpha_int[0];
    float a[BBASIS];
    float mx = -1e30f;
    #pragma unroll
    for (int b = 0; b < BBASIS; ++b) { a[b] = alphas[ai * BBASIS + b]; mx = fmaxf(mx, a[b]); }
    float ssum = 0.f;
    #pragma unroll
    for (int b = 0; b < BBASIS; ++b) { a[b] = expf(a[b] - mx); ssum += a[b]; }
    const float inv_s = 1.f / ssum;

    // ---- igates: ig_lds[r][t] = dot(x[t,:], v[j,:]) for this wave's 2 rows ----
    {
        float vr[2][8][4];
        #pragma unroll
        for (int j2 = 0; j2 < 2; ++j2) {
            const float4* vrow = (const float4*)(v + (size_t)(j0 + j2) * HDIM);
            #pragma unroll
            for (int k = 0; k < 8; ++k) {
                float4 t4 = vrow[lane + 64 * k];
                vr[j2][k][0] = t4.x; vr[j2][k][1] = t4.y; vr[j2][k][2] = t4.z; vr[j2][k][3] = t4.w;
            }
        }
        for (int t = 0; t < TSTEPS; ++t) {
            const float4* xt = (const float4*)(x + (size_t)t * HDIM);
            float acc0 = 0.f, acc1 = 0.f;
            #pragma unroll
            for (int k = 0; k < 8; ++k) {
                float4 x4 = xt[lane + 64 * k];
                acc0 += vr[0][k][0]*x4.x + vr[0][k][1]*x4.y + vr[0][k][2]*x4.z + vr[0][k][3]*x4.w;
                acc1 += vr[1][k][0]*x4.x + vr[1][k][1]*x4.y + vr[1][k][2]*x4.z + vr[1][k][3]*x4.w;
            }
            #pragma unroll
            for (int off = 32; off > 0; off >>= 1) {
                acc0 += __shfl_xor(acc0, off, 64);
                acc1 += __shfl_xor(acc1, off, 64);
            }
            if (lane == 0) {
                ig_lds[wave * 2 + 0][t] = acc0;
                ig_lds[wave * 2 + 1][t] = acc1;
            }
        }
    }

    // ---- u = sum_b alpha[b] * W[b], rows j0/j1 into registers ----
    float u_reg[2][8][4];
    #pragma unroll
    for (int j2 = 0; j2 < 2; ++j2)
        #pragma unroll
        for (int k = 0; k < 8; ++k)
            #pragma unroll
            for (int i = 0; i < 4; ++i) u_reg[j2][k][i] = 0.f;

    for (int b = 0; b < BBASIS; ++b) {
        const float ab = a[b] * inv_s;
        #pragma unroll
        for (int j2 = 0; j2 < 2; ++j2) {
            const float4* wrow = (const float4*)(W + ((size_t)b * HDIM + (size_t)(j0 + j2)) * HDIM);
            #pragma unroll
            for (int k = 0; k < 8; ++k) {
                float4 w4 = wrow[lane + 64 * k];
                u_reg[j2][k][0] += ab * w4.x;
                u_reg[j2][k][1] += ab * w4.y;
                u_reg[j2][k][2] += ab * w4.z;
                u_reg[j2][k][3] += ab * w4.w;
            }
        }
    }
    const float bias0 = bias[j0], bias1 = bias[j1];

    // ---- h0 = 0 ----
    for (int i = tid; i < HDIM; i += NTHR) h_lds[0][i] = 0.f;
    __syncthreads();

    // ---- sequential scan: each step writes a FRESH hbuf slot; consumers poll data ----
    int cur = 0;
    for (int t = 0; t < TSTEPS; ++t) {
        float acc0 = 0.f, acc1 = 0.f;
        #pragma unroll
        for (int k = 0; k < 8; ++k) {
            const f32x4 h4 = ((const f32x4*)h_lds[cur])[lane + 64 * k];
            acc0 += u_reg[0][k][0]*h4.x + u_reg[0][k][1]*h4.y + u_reg[0][k][2]*h4.z + u_reg[0][k][3]*h4.w;
            acc1 += u_reg[1][k][0]*h4.x + u_reg[1][k][1]*h4.y + u_reg[1][k][2]*h4.z + u_reg[1][k][3]*h4.w;
        }
        #pragma unroll
        for (int off = 32; off > 0; off >>= 1) {
            acc0 += __shfl_xor(acc0, off, 64);
            acc1 += __shfl_xor(acc1, off, 64);
        }
        float* hg = hbuf + (size_t)(t + 1) * HDIM;
        if (lane == 0) {
            float hn0 = tanhf(acc0 + ig_lds[wave * 2 + 0][t] + bias0);
            float hn1 = tanhf(acc1 + ig_lds[wave * 2 + 1][t] + bias1);
            f32x2 hv; hv.x = hn0; hv.y = hn1;
            store_coherent_f2(&hg[j0], hv);
        }
        // Poll h_{t+1} directly (arrival of data IS the signal), stage into other LDS buf
        f32x4 ha, hb;
        poll2_f4(hg + 4 * tid, hg + 1024 + 4 * tid, ha, hb);
        const int nxt = cur ^ 1;
        *(f32x4*)&h_lds[nxt][4 * tid]        = ha;
        *(f32x4*)&h_lds[nxt][1024 + 4 * tid] = hb;
        __syncthreads();
        cur = nxt;
    }

    // ---- out = sigmoid(h @ fc_w.T + fc_b) ----
    {
        float acc0 = 0.f, acc1 = 0.f;
        const float4* f0 = (const float4*)(fc_w + (size_t)j0 * HDIM);
        const float4* f1 = (const float4*)(fc_w + (size_t)j1 * HDIM);
        #pragma unroll
        for (int k = 0; k < 8; ++k) {
            const f32x4 h4 = ((const f32x4*)h_lds[cur])[lane + 64 * k];
            float4 w0 = f0[lane + 64 * k];
            float4 w1 = f1[lane + 64 * k];
            acc0 += w0.x*h4.x + w0.y*h4.y + w0.z*h4.z + w0.w*h4.w;
            acc1 += w1.x*h4.x + w1.y*h4.y + w1.z*h4.z + w1.w*h4.w;
        }
        #pragma unroll
        for (int off = 32; off > 0; off >>= 1) {
            acc0 += __shfl_xor(acc0, off, 64);
            acc1 += __shfl_xor(acc1, off, 64);
        }
        if (lane == 0) {
            out[j0] = 1.f / (1.f + expf(-(acc0 + fc_b[j0])));
            out[j1] = 1.f / (1.f + expf(-(acc1 + fc_b[j1])));
        }
    }
}

extern "C" void kernel_launch(void* const* d_in, const int* in_sizes, int n_in,
                              void* d_out, int out_size, void* d_ws, size_t ws_size,
                              hipStream_t stream)
{
    const float* x      = (const float*)d_in[0];
    const float* W      = (const float*)d_in[1];
    const float* alphas = (const float*)d_in[2];
    const float* bias   = (const float*)d_in[3];
    const float* v      = (const float*)d_in[4];
    const float* fc_w   = (const float*)d_in[5];
    const float* fc_b   = (const float*)d_in[6];
    const int*   ai     = (const int*)d_in[7];
    float* out = (float*)d_out;

    float* hbuf = (float*)d_ws;                       // [TSTEPS+1][2048] floats, ~2.06 MB
    const size_t hbuf_bytes = (size_t)(TSTEPS + 1) * HDIM * sizeof(float);

    // Sentinel-fill: 0xFF bytes -> every word = 0xFFFFFFFF (NaN), never a tanh output.
    // Required every launch (graph replays do not re-poison d_ws).
    hipMemsetAsync(d_ws, 0xFF, hbuf_bytes, stream);

    elman_scan_kernel<<<NBLK, NTHR, 0, stream>>>(x, W, alphas, bias, v, fc_w, fc_b,
                                                 ai, out, hbuf);
}